// Round 5
// baseline (794.173 us; speedup 1.0000x reference)
//
#include <hip/hip_runtime.h>

#define N_USER 50000
#define N_ITEM 100000
#define NTOT   150000
#define D      64
#define NNZ    2400000
#define NEG_SLOPE 0.01f

#define BSHIFT 10
#define NB     147            // ceil(NTOT / 1024)
#define P1_PER 4096           // entries per block in binning passes (1024 thr x 4)
#define NBLK1  586            // ceil(NNZ / P1_PER)

typedef unsigned int uint;
typedef unsigned short ushort;
typedef _Float16 h4 __attribute__((ext_vector_type(4)));
typedef float f4 __attribute__((ext_vector_type(4)));

__device__ inline uint bf16rne(float x) {           // f32 -> bf16 bits (RNE)
    uint b = __float_as_uint(x);
    return (b + 0x7FFFu + ((b >> 16) & 1u)) >> 16;
}
__device__ inline float bf_lo(uint u) { return __uint_as_float(u << 16); }
__device__ inline float bf_hi(uint u) { return __uint_as_float(u & 0xFFFF0000u); }

// ---------------- concat user+item embeddings -> bf16 ego0 ----------------
__global__ void k_concat16(const float* __restrict__ u, const float* __restrict__ it,
                           ushort* __restrict__ A16) {
    int i = blockIdx.x * 256 + threadIdx.x;          // float4 index, exact grid 2.4M
    const int nu4 = N_USER * D / 4;
    float4 v = (i < nu4) ? ((const float4*)u)[i] : ((const float4*)it)[i - nu4];
    uint lo = bf16rne(v.x) | (bf16rne(v.y) << 16);
    uint hi = bf16rne(v.z) | (bf16rne(v.w) << 16);
    ((uint2*)A16)[i] = make_uint2(lo, hi);
}

__global__ void k_bzero(int* __restrict__ bcnt) {
    int t = threadIdx.x;
    if (t < NB) bcnt[t] = 0;
}

// ---------------- bucket histogram (LDS-aggregated) ----------------
__global__ __launch_bounds__(1024) void k_bhist(const int* __restrict__ rows,
                                                int* __restrict__ bcnt) {
    __shared__ int lcnt[NB];
    int tid = threadIdx.x;
    if (tid < NB) lcnt[tid] = 0;
    __syncthreads();
    int base = blockIdx.x * P1_PER;
    #pragma unroll
    for (int k = 0; k < 4; ++k) {
        int i = base + k * 1024 + tid;
        if (i < NNZ) atomicAdd(&lcnt[rows[i] >> BSHIFT], 1);
    }
    __syncthreads();
    if (tid < NB) atomicAdd(&bcnt[tid], lcnt[tid]);
}

__global__ void k_bscan(const int* __restrict__ bcnt, int* __restrict__ bptr,
                        int* __restrict__ bcur) {
    __shared__ int s[256];
    int tid = threadIdx.x;
    int v = (tid < NB) ? bcnt[tid] : 0;
    s[tid] = v; __syncthreads();
    for (int off = 1; off < 256; off <<= 1) {
        int t = (tid >= off) ? s[tid - off] : 0;
        __syncthreads();
        s[tid] += t;
        __syncthreads();
    }
    if (tid < NB) { int ex = s[tid] - v; bptr[tid] = ex; bcur[tid] = ex; }
    if (tid == NB - 1) bptr[NB] = s[tid];
}

// ---------------- pass 1: bin entries bucket-major ----------------
__global__ __launch_bounds__(1024) void k_binpass1(const int* __restrict__ rows,
                                                   const int* __restrict__ cols,
                                                   const float* __restrict__ vals,
                                                   int* __restrict__ bcur,
                                                   int2* __restrict__ bucketed) {
    __shared__ int lcnt[NB], lbase[NB];
    int tid = threadIdx.x;
    int base = blockIdx.x * P1_PER;
    if (tid < NB) lcnt[tid] = 0;
    __syncthreads();
    int r[4];
    #pragma unroll
    for (int k = 0; k < 4; ++k) {
        int i = base + k * 1024 + tid;
        r[k] = (i < NNZ) ? rows[i] : -1;
        if (r[k] >= 0) atomicAdd(&lcnt[r[k] >> BSHIFT], 1);
    }
    __syncthreads();
    if (tid < NB) { lbase[tid] = atomicAdd(&bcur[tid], lcnt[tid]); lcnt[tid] = 0; }
    __syncthreads();
    #pragma unroll
    for (int k = 0; k < 4; ++k) {
        int i = base + k * 1024 + tid;
        if (r[k] >= 0) {
            int b = r[k] >> BSHIFT;
            int off = atomicAdd(&lcnt[b], 1);
            bucketed[lbase[b] + off] =
                make_int2(((r[k] & 1023) << 18) | cols[i], __float_as_int(vals[i]));
        }
    }
}

// ---------------- pass 2: per-bucket CSR build ----------------
__global__ __launch_bounds__(1024) void k_binpass2(const int* __restrict__ bptr,
                                                   const int2* __restrict__ bucketed,
                                                   int* __restrict__ ptr,
                                                   int2* __restrict__ csr) {
    __shared__ int c0[1024], px[1024];
    int tid = threadIdx.x, b = blockIdx.x;
    int s = bptr[b], e = bptr[b + 1];
    c0[tid] = 0;
    __syncthreads();
    for (int i = s + tid; i < e; i += 1024) atomicAdd(&c0[bucketed[i].x >> 18], 1);
    __syncthreads();
    int v = c0[tid];
    px[tid] = v;
    __syncthreads();
    for (int off = 1; off < 1024; off <<= 1) {
        int t = (tid >= off) ? px[tid - off] : 0;
        __syncthreads();
        px[tid] += t;
        __syncthreads();
    }
    int ex = px[tid] - v;
    int r = (b << BSHIFT) + tid;
    if (r <= NTOT) ptr[r] = s + ex;
    px[tid] = ex;
    c0[tid] = 0;
    __syncthreads();
    for (int i = s + tid; i < e; i += 1024) {
        int2 e2 = bucketed[i];
        int lr = e2.x >> 18;
        int off = atomicAdd(&c0[lr], 1);
        csr[s + px[lr] + off] = make_int2(e2.x & 0x3FFFF, e2.y);
    }
}

// -------- SpMM: wave/row, scalar CSR broadcast, 16 entries/iter, bf16 gathers --------
__global__ __launch_bounds__(256) void k_spmm(const int* __restrict__ ptr,
                                              const int2* __restrict__ csr,
                                              const ushort* __restrict__ E16,
                                              float* __restrict__ Lout) {
    int lane = threadIdx.x & 63;
    int half = lane >> 5;
    int l32  = lane & 31;
    int r = __builtin_amdgcn_readfirstlane(blockIdx.x * 4 + (threadIdx.x >> 6));
    int start = ptr[r], end = ptr[r + 1];
    float acc0 = 0.f, acc1 = 0.f;
    const uint* E32 = (const uint*)E16;              // [c*32 + l32] = cols (2*l32, 2*l32+1)
    int j = start;
    for (; j + 15 < end; j += 16) {                  // 8 gather-lines in flight
        int2 q[16];
        #pragma unroll
        for (int i = 0; i < 16; ++i) q[i] = csr[j + i];   // uniform -> scalar loads
        uint u[8]; float v[8];
        #pragma unroll
        for (int i = 0; i < 8; ++i) {
            int c = half ? q[2 * i + 1].x : q[2 * i].x;
            v[i] = __int_as_float(half ? q[2 * i + 1].y : q[2 * i].y);
            u[i] = E32[(c << 5) + l32];
        }
        #pragma unroll
        for (int i = 0; i < 8; ++i) {
            acc0 += v[i] * bf_lo(u[i]);  acc1 += v[i] * bf_hi(u[i]);
        }
    }
    for (; j + 7 < end; j += 8) {
        int2 q[8];
        #pragma unroll
        for (int i = 0; i < 8; ++i) q[i] = csr[j + i];
        uint u[4]; float v[4];
        #pragma unroll
        for (int i = 0; i < 4; ++i) {
            int c = half ? q[2 * i + 1].x : q[2 * i].x;
            v[i] = __int_as_float(half ? q[2 * i + 1].y : q[2 * i].y);
            u[i] = E32[(c << 5) + l32];
        }
        #pragma unroll
        for (int i = 0; i < 4; ++i) {
            acc0 += v[i] * bf_lo(u[i]);  acc1 += v[i] * bf_hi(u[i]);
        }
    }
    for (; j + 1 < end; j += 2) {
        int2 ea = csr[j], eb = csr[j + 1];
        int c   = half ? eb.x : ea.x;
        float v = __int_as_float(half ? eb.y : ea.y);
        uint u = E32[(c << 5) + l32];
        acc0 += v * bf_lo(u);  acc1 += v * bf_hi(u);
    }
    if (j < end) {
        int2 ea = csr[j];
        if (half == 0) {
            uint u = E32[(ea.x << 5) + l32];
            float v = __int_as_float(ea.y);
            acc0 += v * bf_lo(u);  acc1 += v * bf_hi(u);
        }
    }
    acc0 += __shfl_xor(acc0, 32, 64);
    acc1 += __shfl_xor(acc1, 32, 64);
    if (half == 0)
        *(float2*)&Lout[r * D + l32 * 2] = make_float2(acc0, acc1);
}

// ---- MFMA transform: ego_new = leaky((L+E)@Wgc + (L*E)@Wbi + 2b) -> bf16 ----
// v_mfma_f32_16x16x16_f16: A lane l -> row l&15, k=(l>>4)*4+j; B symmetric;
// D lane l reg i -> row (l>>4)*4+i, col l&15.
__global__ __launch_bounds__(256) void k_transform_mfma(
        const ushort* __restrict__ E16, const float* __restrict__ L,
        const float* __restrict__ Wgc, const float* __restrict__ Wbi,
        const float* __restrict__ bb, ushort* __restrict__ O16, int n) {
    __shared__ _Float16 ldsW[2 * 16 * 256];   // 16KB: [m][ks*4+nt][n'*16+k'] (k' contiguous)
    __shared__ ushort   ldsO[4][16 * 72];     // per-wave 16x64 bf16 tile, pitch 72 (144B)
    int tid = threadIdx.x;

    #pragma unroll
    for (int m = 0; m < 2; ++m) {
        const float* W = m ? Wbi : Wgc;
        for (int idx = tid; idx < 4096; idx += 256) {
            int k = idx >> 6, nn = idx & 63;
            ldsW[(m * 16 + (k >> 4) * 4 + (nn >> 4)) * 256 + (nn & 15) * 16 + (k & 15)] =
                (_Float16)W[idx];
        }
    }
    __syncthreads();

    int l = tid & 63, w = tid >> 6;
    int g = l >> 4, r16 = l & 15;

    // B-fragments: one ds_read_b64 each, persistent in registers
    h4 bfrag[2][4][4];
    #pragma unroll
    for (int m = 0; m < 2; ++m)
        #pragma unroll
        for (int ks = 0; ks < 4; ++ks)
            #pragma unroll
            for (int nt = 0; nt < 4; ++nt)
                bfrag[m][ks][nt] =
                    *(const h4*)&ldsW[(m * 16 + ks * 4 + nt) * 256 + r16 * 16 + g * 4];

    for (int t = 0; t < 4; ++t) {
        int tile = blockIdx.x * 4 + t;
        int rowbase = tile * 64 + w * 16;
        int r = rowbase + r16;
        int rc = min(r, n - 1);

        h4 x1[4], x2[4];
        #pragma unroll
        for (int ks = 0; ks < 4; ++ks) {
            int c = ks * 16 + g * 4;
            float4 lf = *(const float4*)&L[rc * D + c];
            uint2  eu = *(const uint2*)&E16[rc * D + c];
            float e0 = bf_lo(eu.x), e1 = bf_hi(eu.x);
            float e2 = bf_lo(eu.y), e3 = bf_hi(eu.y);
            x1[ks][0] = (_Float16)(lf.x + e0); x1[ks][1] = (_Float16)(lf.y + e1);
            x1[ks][2] = (_Float16)(lf.z + e2); x1[ks][3] = (_Float16)(lf.w + e3);
            x2[ks][0] = (_Float16)(lf.x * e0); x2[ks][1] = (_Float16)(lf.y * e1);
            x2[ks][2] = (_Float16)(lf.z * e2); x2[ks][3] = (_Float16)(lf.w * e3);
        }

        f4 acc[4];
        #pragma unroll
        for (int nt = 0; nt < 4; ++nt) acc[nt] = (f4){0.f, 0.f, 0.f, 0.f};
        #pragma unroll
        for (int ks = 0; ks < 4; ++ks)
            #pragma unroll
            for (int nt = 0; nt < 4; ++nt)
                acc[nt] = __builtin_amdgcn_mfma_f32_16x16x16f16(x1[ks], bfrag[0][ks][nt],
                                                                acc[nt], 0, 0, 0);
        #pragma unroll
        for (int ks = 0; ks < 4; ++ks)
            #pragma unroll
            for (int nt = 0; nt < 4; ++nt)
                acc[nt] = __builtin_amdgcn_mfma_f32_16x16x16f16(x2[ks], bfrag[1][ks][nt],
                                                                acc[nt], 0, 0, 0);

        // epilogue: bias + leaky -> bf16 LDS tile -> coalesced store
        #pragma unroll
        for (int nt = 0; nt < 4; ++nt) {
            int col = nt * 16 + r16;
            float bv = 2.f * bb[col];
            #pragma unroll
            for (int i = 0; i < 4; ++i) {
                float y = acc[nt][i] + bv;
                y = (y >= 0.f) ? y : NEG_SLOPE * y;
                ldsO[w][(g * 4 + i) * 72 + col] = (ushort)bf16rne(y);
            }
        }
        int lr = l >> 2;
        int rowg = rowbase + lr;
        if (rowg < n) {
            const ushort* src = &ldsO[w][lr * 72 + (l & 3) * 16];
            uint4 v0 = *(const uint4*)src;
            uint4 v1 = *(const uint4*)(src + 8);
            *(uint4*)&O16[rowg * D + (l & 3) * 16] = v0;
            *(uint4*)&O16[rowg * D + (l & 3) * 16 + 8] = v1;
        }
    }
}

// ---------------- gathers into output ----------------
__global__ void k_gather0(const float* __restrict__ u, const float* __restrict__ it,
                          const int* __restrict__ users, const int* __restrict__ pos,
                          const int* __restrict__ neg, float* __restrict__ out) {
    int lane = threadIdx.x & 63;
    int gi = blockIdx.x * 4 + (threadIdx.x >> 6);
    int g = gi >> 12, b = gi & 4095;
    const float* src = (g == 0) ? (u + (size_t)users[b] * D)
                                : (it + (size_t)((g == 1) ? pos[b] : neg[b]) * D);
    out[gi * 256 + lane] = src[lane];
}

__global__ void k_gathern(const ushort* __restrict__ E16, const int* __restrict__ users,
                          const int* __restrict__ pos, const int* __restrict__ neg,
                          float* __restrict__ out, int layer) {
    int lane = threadIdx.x & 63;
    int gi = blockIdx.x * 4 + (threadIdx.x >> 6);
    int g = gi >> 12, b = gi & 4095;
    int src = (g == 0) ? users[b] : (N_USER + ((g == 1) ? pos[b] : neg[b]));
    float v = __uint_as_float(((uint)E16[src * D + lane]) << 16);
    float ss = v * v;
    #pragma unroll
    for (int off = 32; off >= 1; off >>= 1) ss += __shfl_xor(ss, off, 64);
    float dnm = fmaxf(sqrtf(ss), 1e-12f);
    out[gi * 256 + layer * D + lane] = v / dnm;
}

extern "C" void kernel_launch(void* const* d_in, const int* in_sizes, int n_in,
                              void* d_out, int out_size, void* d_ws, size_t ws_size,
                              hipStream_t stream) {
    const float* user_emb = (const float*)d_in[0];
    const float* item_emb = (const float*)d_in[1];
    const float* W_gc     = (const float*)d_in[2];
    const float* W_bi     = (const float*)d_in[3];
    const float* b_bi     = (const float*)d_in[4];
    const float* vals     = (const float*)d_in[5];
    const int*   rows     = (const int*)d_in[6];
    const int*   cols     = (const int*)d_in[7];
    const int*   users    = (const int*)d_in[8];
    const int*   pos      = (const int*)d_in[9];
    const int*   neg      = (const int*)d_in[10];
    float* out = (float*)d_out;

    char* ws = (char*)d_ws;
    size_t off = 0;
    auto alloc = [&](size_t b) { void* p = ws + off; off += (b + 255) & ~(size_t)255; return p; };
    ushort* Ea  = (ushort*)alloc((size_t)NTOT * D * 2);   // bf16 ego (ping)
    ushort* Eb  = (ushort*)alloc((size_t)NTOT * D * 2);   // bf16 ego (pong)
    float*  L   = (float*) alloc((size_t)NTOT * D * 4);   // f32 spmm output
    int2*   csr = (int2*)  alloc((size_t)NNZ * 8);
    int*    ptr = (int*)   alloc((size_t)(NTOT + 1) * 4);
    int*    bptr= (int*)   alloc((NB + 1) * 4);
    int*    bcnt= (int*)   alloc(NB * 4);
    int*    bcur= (int*)   alloc(NB * 4);
    int2*   bucketed = (int2*)L;   // alias: dead before first spmm writes L
    (void)ws_size;

    hipLaunchKernelGGL(k_concat16, dim3(9375), dim3(256),  0, stream, user_emb, item_emb, Ea);
    hipLaunchKernelGGL(k_bzero,    dim3(1),    dim3(256),  0, stream, bcnt);
    hipLaunchKernelGGL(k_bhist,    dim3(NBLK1),dim3(1024), 0, stream, rows, bcnt);
    hipLaunchKernelGGL(k_bscan,    dim3(1),    dim3(256),  0, stream, bcnt, bptr, bcur);
    hipLaunchKernelGGL(k_binpass1, dim3(NBLK1),dim3(1024), 0, stream, rows, cols, vals, bcur, bucketed);
    hipLaunchKernelGGL(k_binpass2, dim3(NB),   dim3(1024), 0, stream, bptr, bucketed, ptr, csr);
    hipLaunchKernelGGL(k_gather0,  dim3(3072), dim3(256),  0, stream, user_emb, item_emb, users, pos, neg, out);

    ushort* cur = Ea; ushort* nxt = Eb;
    for (int k = 0; k < 3; ++k) {
        hipLaunchKernelGGL(k_spmm,           dim3(37500), dim3(256), 0, stream, ptr, csr, cur, L);
        hipLaunchKernelGGL(k_transform_mfma, dim3(586),   dim3(256), 0, stream, cur, L,
                           W_gc + k * 4096, W_bi + k * 4096, b_bi + k * 64, nxt, NTOT);
        hipLaunchKernelGGL(k_gathern,        dim3(3072),  dim3(256), 0, stream, nxt, users, pos, neg, out, k + 1);
        ushort* t = cur; cur = nxt; nxt = t;
    }
}

// Round 6
// 442.114 us; speedup vs baseline: 1.7963x; 1.7963x over previous
//
#include <hip/hip_runtime.h>

#define N_USER 50000
#define N_ITEM 100000
#define NTOT   150000
#define D      64
#define NNZ    2400000
#define NEG_SLOPE 0.01f

#define BSHIFT 10
#define NB     147            // ceil(NTOT / 1024)
#define P1_PER 4096           // entries per block in binning passes (1024 thr x 4)
#define NBLK1  586            // ceil(NNZ / P1_PER)

typedef unsigned int uint;
typedef unsigned short ushort;
typedef _Float16 h4 __attribute__((ext_vector_type(4)));
typedef float f4 __attribute__((ext_vector_type(4)));

__device__ inline uint bf16rne(float x) {           // f32 -> bf16 bits (RNE)
    uint b = __float_as_uint(x);
    return (b + 0x7FFFu + ((b >> 16) & 1u)) >> 16;
}
__device__ inline float bf_lo(uint u) { return __uint_as_float(u << 16); }
__device__ inline float bf_hi(uint u) { return __uint_as_float(u & 0xFFFF0000u); }

// ---------------- concat user+item embeddings -> bf16 ego0 ----------------
__global__ void k_concat16(const float* __restrict__ u, const float* __restrict__ it,
                           ushort* __restrict__ A16) {
    int i = blockIdx.x * 256 + threadIdx.x;          // float4 index, exact grid 2.4M
    const int nu4 = N_USER * D / 4;
    float4 v = (i < nu4) ? ((const float4*)u)[i] : ((const float4*)it)[i - nu4];
    uint lo = bf16rne(v.x) | (bf16rne(v.y) << 16);
    uint hi = bf16rne(v.z) | (bf16rne(v.w) << 16);
    ((uint2*)A16)[i] = make_uint2(lo, hi);
}

__global__ void k_bzero(int* __restrict__ bcnt) {
    int t = threadIdx.x;
    if (t < NB) bcnt[t] = 0;
}

// ---------------- bucket histogram (LDS-aggregated) ----------------
__global__ __launch_bounds__(1024) void k_bhist(const int* __restrict__ rows,
                                                int* __restrict__ bcnt) {
    __shared__ int lcnt[NB];
    int tid = threadIdx.x;
    if (tid < NB) lcnt[tid] = 0;
    __syncthreads();
    int base = blockIdx.x * P1_PER;
    #pragma unroll
    for (int k = 0; k < 4; ++k) {
        int i = base + k * 1024 + tid;
        if (i < NNZ) atomicAdd(&lcnt[rows[i] >> BSHIFT], 1);
    }
    __syncthreads();
    if (tid < NB) atomicAdd(&bcnt[tid], lcnt[tid]);
}

__global__ void k_bscan(const int* __restrict__ bcnt, int* __restrict__ bptr,
                        int* __restrict__ bcur) {
    __shared__ int s[256];
    int tid = threadIdx.x;
    int v = (tid < NB) ? bcnt[tid] : 0;
    s[tid] = v; __syncthreads();
    for (int off = 1; off < 256; off <<= 1) {
        int t = (tid >= off) ? s[tid - off] : 0;
        __syncthreads();
        s[tid] += t;
        __syncthreads();
    }
    if (tid < NB) { int ex = s[tid] - v; bptr[tid] = ex; bcur[tid] = ex; }
    if (tid == NB - 1) bptr[NB] = s[tid];
}

// ---------------- pass 1: bin entries bucket-major ----------------
__global__ __launch_bounds__(1024) void k_binpass1(const int* __restrict__ rows,
                                                   const int* __restrict__ cols,
                                                   const float* __restrict__ vals,
                                                   int* __restrict__ bcur,
                                                   int2* __restrict__ bucketed) {
    __shared__ int lcnt[NB], lbase[NB];
    int tid = threadIdx.x;
    int base = blockIdx.x * P1_PER;
    if (tid < NB) lcnt[tid] = 0;
    __syncthreads();
    int r[4];
    #pragma unroll
    for (int k = 0; k < 4; ++k) {
        int i = base + k * 1024 + tid;
        r[k] = (i < NNZ) ? rows[i] : -1;
        if (r[k] >= 0) atomicAdd(&lcnt[r[k] >> BSHIFT], 1);
    }
    __syncthreads();
    if (tid < NB) { lbase[tid] = atomicAdd(&bcur[tid], lcnt[tid]); lcnt[tid] = 0; }
    __syncthreads();
    #pragma unroll
    for (int k = 0; k < 4; ++k) {
        int i = base + k * 1024 + tid;
        if (r[k] >= 0) {
            int b = r[k] >> BSHIFT;
            int off = atomicAdd(&lcnt[b], 1);
            bucketed[lbase[b] + off] =
                make_int2(((r[k] & 1023) << 18) | cols[i], __float_as_int(vals[i]));
        }
    }
}

// ---------------- pass 2: per-bucket CSR build ----------------
__global__ __launch_bounds__(1024) void k_binpass2(const int* __restrict__ bptr,
                                                   const int2* __restrict__ bucketed,
                                                   int* __restrict__ ptr,
                                                   int2* __restrict__ csr) {
    __shared__ int c0[1024], px[1024];
    int tid = threadIdx.x, b = blockIdx.x;
    int s = bptr[b], e = bptr[b + 1];
    c0[tid] = 0;
    __syncthreads();
    for (int i = s + tid; i < e; i += 1024) atomicAdd(&c0[bucketed[i].x >> 18], 1);
    __syncthreads();
    int v = c0[tid];
    px[tid] = v;
    __syncthreads();
    for (int off = 1; off < 1024; off <<= 1) {
        int t = (tid >= off) ? px[tid - off] : 0;
        __syncthreads();
        px[tid] += t;
        __syncthreads();
    }
    int ex = px[tid] - v;
    int r = (b << BSHIFT) + tid;
    if (r <= NTOT) ptr[r] = s + ex;
    px[tid] = ex;
    c0[tid] = 0;
    __syncthreads();
    for (int i = s + tid; i < e; i += 1024) {
        int2 e2 = bucketed[i];
        int lr = e2.x >> 18;
        int off = atomicAdd(&c0[lr], 1);
        csr[s + px[lr] + off] = make_int2(e2.x & 0x3FFFF, e2.y);
    }
}

// -------- SpMM: wave/row, scalar CSR broadcast, named 16-entry unroll --------
__global__ __launch_bounds__(256) void k_spmm(const int* __restrict__ ptr,
                                              const int2* __restrict__ csr,
                                              const ushort* __restrict__ E16,
                                              float* __restrict__ Lout) {
    int lane = threadIdx.x & 63;
    int half = lane >> 5;
    int l32  = lane & 31;
    int r = __builtin_amdgcn_readfirstlane(blockIdx.x * 4 + (threadIdx.x >> 6));
    int start = ptr[r], end = ptr[r + 1];
    float acc0 = 0.f, acc1 = 0.f;
    const uint* E32 = (const uint*)E16;              // [c*32 + l32] = cols (2*l32, 2*l32+1)
    int j = start;
    for (; j + 15 < end; j += 16) {                  // 8 gather-lines in flight, all named
        int2 ea0 = csr[j + 0],  ea1 = csr[j + 1],  ea2 = csr[j + 2],  ea3 = csr[j + 3];
        int2 ea4 = csr[j + 4],  ea5 = csr[j + 5],  ea6 = csr[j + 6],  ea7 = csr[j + 7];
        int2 ea8 = csr[j + 8],  ea9 = csr[j + 9],  eaA = csr[j + 10], eaB = csr[j + 11];
        int2 eaC = csr[j + 12], eaD = csr[j + 13], eaE = csr[j + 14], eaF = csr[j + 15];
        int c0 = half ? ea1.x : ea0.x;
        int c1 = half ? ea3.x : ea2.x;
        int c2 = half ? ea5.x : ea4.x;
        int c3 = half ? ea7.x : ea6.x;
        int c4 = half ? ea9.x : ea8.x;
        int c5 = half ? eaB.x : eaA.x;
        int c6 = half ? eaD.x : eaC.x;
        int c7 = half ? eaF.x : eaE.x;
        uint u0 = E32[(c0 << 5) + l32];
        uint u1 = E32[(c1 << 5) + l32];
        uint u2 = E32[(c2 << 5) + l32];
        uint u3 = E32[(c3 << 5) + l32];
        uint u4 = E32[(c4 << 5) + l32];
        uint u5 = E32[(c5 << 5) + l32];
        uint u6 = E32[(c6 << 5) + l32];
        uint u7 = E32[(c7 << 5) + l32];
        float v0 = __int_as_float(half ? ea1.y : ea0.y);
        float v1 = __int_as_float(half ? ea3.y : ea2.y);
        float v2 = __int_as_float(half ? ea5.y : ea4.y);
        float v3 = __int_as_float(half ? ea7.y : ea6.y);
        float v4 = __int_as_float(half ? ea9.y : ea8.y);
        float v5 = __int_as_float(half ? eaB.y : eaA.y);
        float v6 = __int_as_float(half ? eaD.y : eaC.y);
        float v7 = __int_as_float(half ? eaF.y : eaE.y);
        acc0 += v0 * bf_lo(u0);  acc1 += v0 * bf_hi(u0);
        acc0 += v1 * bf_lo(u1);  acc1 += v1 * bf_hi(u1);
        acc0 += v2 * bf_lo(u2);  acc1 += v2 * bf_hi(u2);
        acc0 += v3 * bf_lo(u3);  acc1 += v3 * bf_hi(u3);
        acc0 += v4 * bf_lo(u4);  acc1 += v4 * bf_hi(u4);
        acc0 += v5 * bf_lo(u5);  acc1 += v5 * bf_hi(u5);
        acc0 += v6 * bf_lo(u6);  acc1 += v6 * bf_hi(u6);
        acc0 += v7 * bf_lo(u7);  acc1 += v7 * bf_hi(u7);
    }
    for (; j + 7 < end; j += 8) {
        int2 ea = csr[j + 0], eb = csr[j + 1];
        int2 ec = csr[j + 2], ed = csr[j + 3];
        int2 ee = csr[j + 4], ef = csr[j + 5];
        int2 eg = csr[j + 6], eh = csr[j + 7];
        int c0 = half ? eb.x : ea.x;
        int c1 = half ? ed.x : ec.x;
        int c2 = half ? ef.x : ee.x;
        int c3 = half ? eh.x : eg.x;
        uint u0 = E32[(c0 << 5) + l32];
        uint u1 = E32[(c1 << 5) + l32];
        uint u2 = E32[(c2 << 5) + l32];
        uint u3 = E32[(c3 << 5) + l32];
        float v0 = __int_as_float(half ? eb.y : ea.y);
        float v1 = __int_as_float(half ? ed.y : ec.y);
        float v2 = __int_as_float(half ? ef.y : ee.y);
        float v3 = __int_as_float(half ? eh.y : eg.y);
        acc0 += v0 * bf_lo(u0);  acc1 += v0 * bf_hi(u0);
        acc0 += v1 * bf_lo(u1);  acc1 += v1 * bf_hi(u1);
        acc0 += v2 * bf_lo(u2);  acc1 += v2 * bf_hi(u2);
        acc0 += v3 * bf_lo(u3);  acc1 += v3 * bf_hi(u3);
    }
    for (; j + 1 < end; j += 2) {
        int2 ea = csr[j], eb = csr[j + 1];
        int c   = half ? eb.x : ea.x;
        float v = __int_as_float(half ? eb.y : ea.y);
        uint u = E32[(c << 5) + l32];
        acc0 += v * bf_lo(u);  acc1 += v * bf_hi(u);
    }
    if (j < end) {
        int2 ea = csr[j];
        if (half == 0) {
            uint u = E32[(ea.x << 5) + l32];
            float v = __int_as_float(ea.y);
            acc0 += v * bf_lo(u);  acc1 += v * bf_hi(u);
        }
    }
    acc0 += __shfl_xor(acc0, 32, 64);
    acc1 += __shfl_xor(acc1, 32, 64);
    if (half == 0)
        *(float2*)&Lout[r * D + l32 * 2] = make_float2(acc0, acc1);
}

// ---- MFMA transform: ego_new = leaky((L+E)@Wgc + (L*E)@Wbi + 2b) -> bf16 ----
// v_mfma_f32_16x16x16_f16: A lane l -> row l&15, k=(l>>4)*4+j; B symmetric;
// D lane l reg i -> row (l>>4)*4+i, col l&15.
__global__ __launch_bounds__(256) void k_transform_mfma(
        const ushort* __restrict__ E16, const float* __restrict__ L,
        const float* __restrict__ Wgc, const float* __restrict__ Wbi,
        const float* __restrict__ bb, ushort* __restrict__ O16, int n) {
    __shared__ _Float16 ldsW[2 * 16 * 256];   // 16KB: [m][ks*4+nt][n'*16+k'] (k' contiguous)
    __shared__ ushort   ldsO[4][16 * 72];     // per-wave 16x64 bf16 tile, pitch 72 (144B)
    int tid = threadIdx.x;

    #pragma unroll
    for (int m = 0; m < 2; ++m) {
        const float* W = m ? Wbi : Wgc;
        for (int idx = tid; idx < 4096; idx += 256) {
            int k = idx >> 6, nn = idx & 63;
            ldsW[(m * 16 + (k >> 4) * 4 + (nn >> 4)) * 256 + (nn & 15) * 16 + (k & 15)] =
                (_Float16)W[idx];
        }
    }
    __syncthreads();

    int l = tid & 63, w = tid >> 6;
    int g = l >> 4, r16 = l & 15;

    // B-fragments: one ds_read_b64 each, persistent in registers
    h4 bfrag[2][4][4];
    #pragma unroll
    for (int m = 0; m < 2; ++m)
        #pragma unroll
        for (int ks = 0; ks < 4; ++ks)
            #pragma unroll
            for (int nt = 0; nt < 4; ++nt)
                bfrag[m][ks][nt] =
                    *(const h4*)&ldsW[(m * 16 + ks * 4 + nt) * 256 + r16 * 16 + g * 4];

    for (int t = 0; t < 4; ++t) {
        int tile = blockIdx.x * 4 + t;
        int rowbase = tile * 64 + w * 16;
        int r = rowbase + r16;
        int rc = min(r, n - 1);

        h4 x1[4], x2[4];
        #pragma unroll
        for (int ks = 0; ks < 4; ++ks) {
            int c = ks * 16 + g * 4;
            float4 lf = *(const float4*)&L[rc * D + c];
            uint2  eu = *(const uint2*)&E16[rc * D + c];
            float e0 = bf_lo(eu.x), e1 = bf_hi(eu.x);
            float e2 = bf_lo(eu.y), e3 = bf_hi(eu.y);
            x1[ks][0] = (_Float16)(lf.x + e0); x1[ks][1] = (_Float16)(lf.y + e1);
            x1[ks][2] = (_Float16)(lf.z + e2); x1[ks][3] = (_Float16)(lf.w + e3);
            x2[ks][0] = (_Float16)(lf.x * e0); x2[ks][1] = (_Float16)(lf.y * e1);
            x2[ks][2] = (_Float16)(lf.z * e2); x2[ks][3] = (_Float16)(lf.w * e3);
        }

        f4 acc[4];
        #pragma unroll
        for (int nt = 0; nt < 4; ++nt) acc[nt] = (f4){0.f, 0.f, 0.f, 0.f};
        #pragma unroll
        for (int ks = 0; ks < 4; ++ks)
            #pragma unroll
            for (int nt = 0; nt < 4; ++nt)
                acc[nt] = __builtin_amdgcn_mfma_f32_16x16x16f16(x1[ks], bfrag[0][ks][nt],
                                                                acc[nt], 0, 0, 0);
        #pragma unroll
        for (int ks = 0; ks < 4; ++ks)
            #pragma unroll
            for (int nt = 0; nt < 4; ++nt)
                acc[nt] = __builtin_amdgcn_mfma_f32_16x16x16f16(x2[ks], bfrag[1][ks][nt],
                                                                acc[nt], 0, 0, 0);

        // epilogue: bias + leaky -> bf16 LDS tile -> coalesced store
        #pragma unroll
        for (int nt = 0; nt < 4; ++nt) {
            int col = nt * 16 + r16;
            float bv = 2.f * bb[col];
            #pragma unroll
            for (int i = 0; i < 4; ++i) {
                float y = acc[nt][i] + bv;
                y = (y >= 0.f) ? y : NEG_SLOPE * y;
                ldsO[w][(g * 4 + i) * 72 + col] = (ushort)bf16rne(y);
            }
        }
        int lr = l >> 2;
        int rowg = rowbase + lr;
        if (rowg < n) {
            const ushort* src = &ldsO[w][lr * 72 + (l & 3) * 16];
            uint4 v0 = *(const uint4*)src;
            uint4 v1 = *(const uint4*)(src + 8);
            *(uint4*)&O16[rowg * D + (l & 3) * 16] = v0;
            *(uint4*)&O16[rowg * D + (l & 3) * 16 + 8] = v1;
        }
    }
}

// ---------------- gathers into output ----------------
__global__ void k_gather0(const float* __restrict__ u, const float* __restrict__ it,
                          const int* __restrict__ users, const int* __restrict__ pos,
                          const int* __restrict__ neg, float* __restrict__ out) {
    int lane = threadIdx.x & 63;
    int gi = blockIdx.x * 4 + (threadIdx.x >> 6);
    int g = gi >> 12, b = gi & 4095;
    const float* src = (g == 0) ? (u + (size_t)users[b] * D)
                                : (it + (size_t)((g == 1) ? pos[b] : neg[b]) * D);
    out[gi * 256 + lane] = src[lane];
}

__global__ void k_gathern(const ushort* __restrict__ E16, const int* __restrict__ users,
                          const int* __restrict__ pos, const int* __restrict__ neg,
                          float* __restrict__ out, int layer) {
    int lane = threadIdx.x & 63;
    int gi = blockIdx.x * 4 + (threadIdx.x >> 6);
    int g = gi >> 12, b = gi & 4095;
    int src = (g == 0) ? users[b] : (N_USER + ((g == 1) ? pos[b] : neg[b]));
    float v = __uint_as_float(((uint)E16[src * D + lane]) << 16);
    float ss = v * v;
    #pragma unroll
    for (int off = 32; off >= 1; off >>= 1) ss += __shfl_xor(ss, off, 64);
    float dnm = fmaxf(sqrtf(ss), 1e-12f);
    out[gi * 256 + layer * D + lane] = v / dnm;
}

extern "C" void kernel_launch(void* const* d_in, const int* in_sizes, int n_in,
                              void* d_out, int out_size, void* d_ws, size_t ws_size,
                              hipStream_t stream) {
    const float* user_emb = (const float*)d_in[0];
    const float* item_emb = (const float*)d_in[1];
    const float* W_gc     = (const float*)d_in[2];
    const float* W_bi     = (const float*)d_in[3];
    const float* b_bi     = (const float*)d_in[4];
    const float* vals     = (const float*)d_in[5];
    const int*   rows     = (const int*)d_in[6];
    const int*   cols     = (const int*)d_in[7];
    const int*   users    = (const int*)d_in[8];
    const int*   pos      = (const int*)d_in[9];
    const int*   neg      = (const int*)d_in[10];
    float* out = (float*)d_out;

    char* ws = (char*)d_ws;
    size_t off = 0;
    auto alloc = [&](size_t b) { void* p = ws + off; off += (b + 255) & ~(size_t)255; return p; };
    ushort* Ea  = (ushort*)alloc((size_t)NTOT * D * 2);   // bf16 ego (ping)
    ushort* Eb  = (ushort*)alloc((size_t)NTOT * D * 2);   // bf16 ego (pong)
    float*  L   = (float*) alloc((size_t)NTOT * D * 4);   // f32 spmm output
    int2*   csr = (int2*)  alloc((size_t)NNZ * 8);
    int*    ptr = (int*)   alloc((size_t)(NTOT + 1) * 4);
    int*    bptr= (int*)   alloc((NB + 1) * 4);
    int*    bcnt= (int*)   alloc(NB * 4);
    int*    bcur= (int*)   alloc(NB * 4);
    int2*   bucketed = (int2*)L;   // alias: dead before first spmm writes L
    (void)ws_size;

    hipLaunchKernelGGL(k_concat16, dim3(9375), dim3(256),  0, stream, user_emb, item_emb, Ea);
    hipLaunchKernelGGL(k_bzero,    dim3(1),    dim3(256),  0, stream, bcnt);
    hipLaunchKernelGGL(k_bhist,    dim3(NBLK1),dim3(1024), 0, stream, rows, bcnt);
    hipLaunchKernelGGL(k_bscan,    dim3(1),    dim3(256),  0, stream, bcnt, bptr, bcur);
    hipLaunchKernelGGL(k_binpass1, dim3(NBLK1),dim3(1024), 0, stream, rows, cols, vals, bcur, bucketed);
    hipLaunchKernelGGL(k_binpass2, dim3(NB),   dim3(1024), 0, stream, bptr, bucketed, ptr, csr);
    hipLaunchKernelGGL(k_gather0,  dim3(3072), dim3(256),  0, stream, user_emb, item_emb, users, pos, neg, out);

    ushort* cur = Ea; ushort* nxt = Eb;
    for (int k = 0; k < 3; ++k) {
        hipLaunchKernelGGL(k_spmm,           dim3(37500), dim3(256), 0, stream, ptr, csr, cur, L);
        hipLaunchKernelGGL(k_transform_mfma, dim3(586),   dim3(256), 0, stream, cur, L,
                           W_gc + k * 4096, W_bi + k * 4096, b_bi + k * 64, nxt, NTOT);
        hipLaunchKernelGGL(k_gathern,        dim3(3072),  dim3(256), 0, stream, nxt, users, pos, neg, out, k + 1);
        ushort* t = cur; cur = nxt; nxt = t;
    }
}